// Round 10
// baseline (204.168 us; speedup 1.0000x reference)
//
#include <hip/hip_runtime.h>
#include <math.h>

// RP scaled-dot-product attention, swapped-QK^T 32x32x16 MFMA flash kernel.
// B=4 H=16 L=1024 Dh=64.  One WG (256 thr, 4 waves) per (bh, 64-query tile).
// Round 10 = VERIFIED round-6 structure with the K/V LDS staging removed:
//   - kf (K A-frags) built direct from global via the qB-pattern pack8f
//     (value-identical to R6's ks LDS contents, derived slot-by-slot).
//   - V A-frags built direct from global via strided cvtpk (value-identical
//     to R6's vt LDS contents; each load instruction = 2x128B segments).
//   - LDS = bias table + mask only (43,264 B) -> 3 blocks/CU (was 2), and
//     NO in-loop barriers (waves decoupled after the table barrier).
// Grid mapping, table build, bias gather, softmax, pf exchange, 2-way merge,
// epilogue: R6 VERBATIM.
//
// 32x32x16 bf16 layouts (C verified m74/m101):
//   A: lane l holds A[l&31][(l>>5)*8+j]   B: lane l holds B[(l>>5)*8+j][l&31]
//   C: lane l reg r holds C[(r&3)+8*(r>>2)+4*(l>>5)][l&31]

#define LL 1024
#define DH 64
#define MAXL 150

typedef __attribute__((ext_vector_type(8)))  short    short8;
typedef __attribute__((ext_vector_type(4)))  float    f32x4;
typedef __attribute__((ext_vector_type(16))) float    f32x16;
typedef __attribute__((ext_vector_type(4)))  unsigned u32x4;

union U4S8 { u32x4 u; short8 s; };

__device__ __forceinline__ unsigned cvtpk(float lo, float hi) {
  unsigned r;
  asm("v_cvt_pk_bf16_f32 %0, %1, %2" : "=v"(r) : "v"(lo), "v"(hi));
  return r;
}
__device__ __forceinline__ float bf2f(unsigned short s) {
  return __uint_as_float((unsigned)s << 16);
}
__device__ __forceinline__ short8 pack8f(float4 a, float4 b) {
  U4S8 t;
  t.u[0] = cvtpk(a.x, a.y); t.u[1] = cvtpk(a.z, a.w);
  t.u[2] = cvtpk(b.x, b.y); t.u[3] = cvtpk(b.z, b.w);
  return t.s;
}
#define KOFF(r) ((((r) & 3)) + 8 * ((r) >> 2))

// LDS carve: table [64][306] u16 = 39,168 B | mask f32 [1024] = 4,096 B
// (merge buffer reuses the table region after the loop: 128*37*4 = 18,944 B)
#define QRS_STRIDE 306
#define OFF_MSK 39168
#define SMEM_SZ 43264

__global__ __launch_bounds__(256, 3)
void rp_attn32(const float* __restrict__ Q, const float* __restrict__ K,
               const float* __restrict__ V, const float* __restrict__ POS,
               const int* __restrict__ MSK, float* __restrict__ OUT) {
  __shared__ __attribute__((aligned(16))) unsigned char smem[SMEM_SZ];
  unsigned short* qrs16 = (unsigned short*)smem;       // [64][306] bias table
  float*          mskf  = (float*)(smem + OFF_MSK);    // [1024]

  const int tid = threadIdx.x;
  // XCD-chunked swizzle (R6 verbatim): XCD d serves bh in [8d,8d+8)
  const int F  = blockIdx.x;
  const int gi = F >> 3;
  const int bh = (F & 7) * 8 + (gi >> 4);
  const int i0 = (gi & 15) * 64;
  const int b  = bh >> 4;

  const int wave = tid >> 6, lane = tid & 63;
  const int lo5 = lane & 31, hi = lane >> 5;
  const int qg = wave & 1, kh = wave >> 1;   // q-group, k-half (R6 verbatim)
  const int qloc = qg * 32 + lo5;
  const int irow = i0 + qloc;

  const size_t bo = (size_t)bh * LL * DH;
  const float* qp = Q + bo;
  const float* kp = K + bo;
  const float* vp = V + bo;
  const int*   mrow = MSK + b * LL;

  // ---- Q^T B-frags (R6 verbatim): qB[c] covers d = c*16 + hi*8 + j ----
  short8 qB[4];
#pragma unroll
  for (int c = 0; c < 4; ++c) {
    const float* src = qp + (size_t)irow * DH + c * 16 + hi * 8;
    qB[c] = pack8f(*(const float4*)src, *(const float4*)(src + 4));
  }

  // ---- mask pre-stage (R6 verbatim) ----
#pragma unroll
  for (int t2 = 0; t2 < 4; ++t2) {
    const int ix = tid + t2 * 256;
    mskf[ix] = mrow[ix] ? -INFINITY : 0.0f;
  }

  // ---- bias table qR^T = pos . Q^T via MFMA (R6 verbatim: wave covers its
  //      qg rows, t-blocks tb = kh, kh+2, ...) ----
  for (int tb = kh; tb < 10; tb += 2) {
    int trow = tb * 32 + lo5; if (trow > 300) trow = 300;
    const float* pr = POS + (size_t)trow * DH;
    f32x16 z;
#pragma unroll
    for (int x = 0; x < 16; ++x) z[x] = 0.f;
#pragma unroll
    for (int c = 0; c < 4; ++c) {
      const float* s2 = pr + c * 16 + hi * 8;
      short8 af = pack8f(*(const float4*)s2, *(const float4*)(s2 + 4));
      z = __builtin_amdgcn_mfma_f32_32x32x16_bf16(af, qB[c], z, 0, 0, 0);
    }
#pragma unroll
    for (int rp = 0; rp < 8; ++rp) {
      const int r = rp * 2;
      int tp = KOFF(r) + 4 * hi + 32 * tb;
      if (tp < 306)  // junk cols 301..305 stay inside the row, never read
        *(unsigned*)(&qrs16[qloc * QRS_STRIDE + tp]) = cvtpk(z[r], z[r + 1]);
    }
  }
  __syncthreads();   // table + mask ready; waves fully decoupled from here

  // ---- flash state (base-2 domain; R6 verbatim) ----
  const float SC = 0.18033688011112042f;  // 0.125 * log2(e)
  float m2 = -1e30f, lsum = 0.f;
  f32x16 acc0, acc1;
#pragma unroll
  for (int x = 0; x < 16; ++x) { acc0[x] = 0.f; acc1[x] = 0.f; }

  for (int rd = 0; rd < 8; ++rd) {
    const int j0 = kh * 512 + rd * 64;   // R6 verbatim

    // ---- K A-frags direct from global (== R6's ks LDS contents) ----
    short8 kf[2][4];
#pragma unroll
    for (int kb = 0; kb < 2; ++kb) {
      const float* krp = kp + (size_t)(j0 + kb * 32 + lo5) * DH + hi * 8;
#pragma unroll
      for (int c = 0; c < 4; ++c)
        kf[kb][c] = pack8f(*(const float4*)(krp + c * 16),
                           *(const float4*)(krp + c * 16 + 4));
    }

    // ---- S^T = K . Q^T (R6 verbatim modulo kf source) ----
    f32x16 st[2];
#pragma unroll
    for (int kb = 0; kb < 2; ++kb) {
      f32x16 z;
#pragma unroll
      for (int x = 0; x < 16; ++x) z[x] = 0.f;
#pragma unroll
      for (int c = 0; c < 4; ++c)
        z = __builtin_amdgcn_mfma_f32_32x32x16_bf16(kf[kb][c], qB[c], z, 0, 0, 0);
      st[kb] = z;
    }

    // ---- bias gather + scale + mask (R6 verbatim) ----
#pragma unroll
    for (int kb = 0; kb < 2; ++kb) {
      const int jb = j0 + kb * 32;
      f32x4 mg[4];
#pragma unroll
      for (int g4 = 0; g4 < 4; ++g4)
        mg[g4] = *(const f32x4*)&mskf[jb + g4 * 8 + 4 * hi];
      const unsigned short* qrow = &qrs16[qloc * QRS_STRIDE];
      const int relmin = jb - (i0 + qg * 32 + 31);
      const int relmax = jb + 31 - (i0 + qg * 32);
      if (relmin >= MAXL) {           // saturates high -> idx 299
        const float bias = bf2f(qrow[299]);
#pragma unroll
        for (int r = 0; r < 16; ++r)
          st[kb][r] = (st[kb][r] + bias) * SC + mg[r >> 2][r & 3];
      } else if (relmax <= -MAXL) {   // saturates low -> wrap row 300
        const float bias = bf2f(qrow[300]);
#pragma unroll
        for (int r = 0; r < 16; ++r)
          st[kb][r] = (st[kb][r] + bias) * SC + mg[r >> 2][r & 3];
      } else {                        // near-diagonal: per-element gather
#pragma unroll
        for (int r = 0; r < 16; ++r) {
          const int rel = jb + KOFF(r) + 4 * hi - irow;
          const int idx = rel <= -MAXL ? 300 : (rel >= MAXL ? 299 : rel + MAXL - 1);
          st[kb][r] = (st[kb][r] + bf2f(qrow[idx])) * SC + mg[r >> 2][r & 3];
        }
      }
    }

    // ---- online softmax with defer-max (R6 verbatim) ----
    f32x16 mx;
#pragma unroll
    for (int r = 0; r < 16; ++r) mx[r] = fmaxf(st[0][r], st[1][r]);
#pragma unroll
    for (int w = 8; w > 0; w >>= 1)
#pragma unroll
      for (int r = 0; r < 8; ++r)
        if (r < w) mx[r] = fmaxf(mx[r], mx[r + w]);
    const float tmax = fmaxf(mx[0], __shfl_xor(mx[0], 32));
    if (!__all(tmax - m2 <= 12.0f)) {
      const float mnew = fmaxf(m2, tmax);
      const float alpha = exp2f(m2 - mnew);
      lsum *= alpha;
      acc0 *= alpha; acc1 *= alpha;
      m2 = mnew;
    }
#pragma unroll
    for (int kb = 0; kb < 2; ++kb)
#pragma unroll
      for (int r = 0; r < 16; ++r) st[kb][r] = exp2f(st[kb][r] - m2);
    f32x16 sx;
#pragma unroll
    for (int r = 0; r < 16; ++r) sx[r] = st[0][r] + st[1][r];
#pragma unroll
    for (int w = 8; w > 0; w >>= 1)
#pragma unroll
      for (int r = 0; r < 8; ++r)
        if (r < w) sx[r] = sx[r] + sx[r + w];
    lsum += sx[0] + __shfl_xor(sx[0], 32);

    // ---- P^T frags (R6 verbatim: cvt_pk pairs + shfl_xor exchange) ----
    short8 pf[4];
#pragma unroll
    for (int ch = 0; ch < 4; ++ch) {
      const int kb = ch >> 1, rb2 = (ch & 1) * 8;
      unsigned a  = cvtpk(st[kb][rb2 + 0], st[kb][rb2 + 1]);
      unsigned a2 = cvtpk(st[kb][rb2 + 2], st[kb][rb2 + 3]);
      unsigned bb = cvtpk(st[kb][rb2 + 4], st[kb][rb2 + 5]);
      unsigned b2 = cvtpk(st[kb][rb2 + 6], st[kb][rb2 + 7]);
      unsigned sa  = __shfl_xor(a, 32);
      unsigned sa2 = __shfl_xor(a2, 32);
      unsigned sbb = __shfl_xor(bb, 32);
      unsigned sb2 = __shfl_xor(b2, 32);
      U4S8 t;
      t.u[0] = hi ? sbb : a;    // k(0,1)  | k(8,9)
      t.u[1] = hi ? sb2 : a2;   // k(2,3)  | k(10,11)
      t.u[2] = hi ? bb  : sa;   // k(4,5)  | k(12,13)
      t.u[3] = hi ? b2  : sa2;  // k(6,7)  | k(14,15)
      pf[ch] = t.s;
    }

    // ---- PV: O^T += V^T . P^T ; V A-frags direct from global
    //      (== R6's vt LDS contents: slot j = bf16(V[j0+ch*16+hi*8+j][d])) ----
#pragma unroll
    for (int ch = 0; ch < 4; ++ch) {
      const float* vcp = vp + (size_t)(j0 + ch * 16 + hi * 8) * DH + lo5;
      U4S8 w0, w1;
#pragma unroll
      for (int p2 = 0; p2 < 4; ++p2) {
        const float x0 = vcp[(2 * p2) * DH],      x1 = vcp[(2 * p2 + 1) * DH];
        const float y0 = vcp[(2 * p2) * DH + 32], y1 = vcp[(2 * p2 + 1) * DH + 32];
        w0.u[p2] = cvtpk(x0, x1);
        w1.u[p2] = cvtpk(y0, y1);
      }
      acc0 = __builtin_amdgcn_mfma_f32_32x32x16_bf16(w0.s, pf[ch], acc0, 0, 0, 0);
      acc1 = __builtin_amdgcn_mfma_f32_32x32x16_bf16(w1.s, pf[ch], acc1, 0, 0, 0);
    }
  }

  // ---- k-half merge (R6 verbatim; buffer reuses table region) ----
  __syncthreads();
  float* mb = (float*)smem;  // 128 lanes * 37 f32 = 18,944 B <= 43,264
  if (wave >= 2) {
    float* d = mb + ((wave - 2) * 64 + lane) * 37;
    d[0] = m2; d[1] = lsum;
#pragma unroll
    for (int r = 0; r < 16; ++r) { d[2 + r] = acc0[r]; d[18 + r] = acc1[r]; }
  }
  __syncthreads();
  if (wave < 2) {
    const float* d = mb + (wave * 64 + lane) * 37;
    const float m1 = d[0], l1 = d[1];
    const float mf = fmaxf(m2, m1);
    const float a0 = exp2f(m2 - mf), a1 = exp2f(m1 - mf);
    const float lf = lsum * a0 + l1 * a1;
    const float inv = 1.f / lf;
    float* op = OUT + bo + (size_t)irow * DH;
#pragma unroll
    for (int r = 0; r < 16; ++r) {
      const int d0 = KOFF(r) + 4 * hi;
      op[d0]      = (acc0[r] * a0 + d[2 + r]  * a1) * inv;
      op[d0 + 32] = (acc1[r] * a0 + d[18 + r] * a1) * inv;
    }
  }
}

extern "C" void kernel_launch(void* const* d_in, const int* in_sizes, int n_in,
                              void* d_out, int out_size, void* d_ws, size_t ws_size,
                              hipStream_t stream) {
  const float* q   = (const float*)d_in[0];
  const float* k   = (const float*)d_in[1];
  const float* v   = (const float*)d_in[2];
  const float* pos = (const float*)d_in[3];
  const int*   msk = (const int*)d_in[4];
  float* out = (float*)d_out;

  rp_attn32<<<dim3(1024), dim3(256), 0, stream>>>(q, k, v, pos, msk, out);
}

// Round 12
// 96.947 us; speedup vs baseline: 2.1060x; 2.1060x over previous
//
#include <hip/hip_runtime.h>
#include <math.h>

// RP scaled-dot-product attention, swapped-QK^T 32x32x16 MFMA flash kernel.
// B=4 H=16 L=1024 Dh=64.  One WG (256 thr, 4 waves) per (bh, 64-query tile).
// Round 12 = VERIFIED round-6 kernel restored verbatim, plus two
// compute-side-only (empirically-safe-class) tweaks:
//   (1) s_setprio(1/0) around the QK^T and PV MFMA clusters (T5 hint).
//   (2) max3-fused 16-element max reduction (T17), same math.
//
// 32x32x16 bf16 layouts (C verified m74/m101):
//   A: lane l holds A[l&31][(l>>5)*8+j]   B: lane l holds B[(l>>5)*8+j][l&31]
//   C: lane l reg r holds C[(r&3)+8*(r>>2)+4*(l>>5)][l&31]

#define LL 1024
#define DH 64
#define MAXL 150

typedef __attribute__((ext_vector_type(8)))  short    short8;
typedef __attribute__((ext_vector_type(4)))  float    f32x4;
typedef __attribute__((ext_vector_type(16))) float    f32x16;
typedef __attribute__((ext_vector_type(4)))  unsigned u32x4;

union U4S8 { u32x4 u; short8 s; };

__device__ __forceinline__ unsigned cvtpk(float lo, float hi) {
  unsigned r;
  asm("v_cvt_pk_bf16_f32 %0, %1, %2" : "=v"(r) : "v"(lo), "v"(hi));
  return r;
}
__device__ __forceinline__ float bf2f(unsigned short s) {
  return __uint_as_float((unsigned)s << 16);
}
__device__ __forceinline__ short8 pack8f(float4 a, float4 b) {
  U4S8 t;
  t.u[0] = cvtpk(a.x, a.y); t.u[1] = cvtpk(a.z, a.w);
  t.u[2] = cvtpk(b.x, b.y); t.u[3] = cvtpk(b.z, b.w);
  return t.s;
}
// byte offset in a 128B-row LDS tile, XOR-swizzled (G4)
__device__ __forceinline__ int swz(int row, int cb) {
  return row * 128 + (cb ^ ((row & 7) << 4));
}
__device__ __forceinline__ void st_pair(unsigned char* base, int row, int colb,
                                        float a, float b) {
  unsigned u = cvtpk(a, b);
  *(unsigned short*)(base + swz(row, colb))     = (unsigned short)u;
  *(unsigned short*)(base + swz(row + 1, colb)) = (unsigned short)(u >> 16);
}
#define KOFF(r) ((((r) & 3)) + 8 * ((r) >> 2))
// fmaxf(fmaxf(a,b),c) fuses to v_max3_f32 on gfx9+ (T17)
__device__ __forceinline__ float max3f(float a, float b, float c) {
  return fmaxf(fmaxf(a, b), c);
}

__global__ __launch_bounds__(256, 2)
void rp_attn32(const float* __restrict__ Q, const float* __restrict__ K,
               const float* __restrict__ V, const float* __restrict__ POS,
               const int* __restrict__ MSK, float* __restrict__ OUT) {
  // qrs: bias table, row stride 306 u16 = 612 B (odd dword stride)
  __shared__ __attribute__((aligned(16))) unsigned short qrs[64][306]; // 39168 B
  __shared__ __attribute__((aligned(16))) unsigned char  kv[32768];    // K h0,h1 | V^T h0,h1
  __shared__ __attribute__((aligned(16))) float          mskf[1024];   // 4096 B

  const int tid = threadIdx.x;
  // XCD-chunked swizzle: XCD d serves bh in [8d,8d+8) -> K/V fits its 4MB L2
  const int F  = blockIdx.x;
  const int gi = F >> 3;
  const int bh = (F & 7) * 8 + (gi >> 4);
  const int i0 = (gi & 15) * 64;
  const int b  = bh >> 4;

  const int wave = tid >> 6, lane = tid & 63;
  const int lo5 = lane & 31, hi = lane >> 5;
  const int qg = wave & 1, kh = wave >> 1;   // q-group, k-half
  const int qloc = qg * 32 + lo5;
  const int irow = i0 + qloc;

  // staging thread mappings
  const int rK = tid >> 2, q4 = tid & 3;     // K: row rK, d-slice q4*16
  const int kkV = tid & 63, dwV = wave;      // V: row kkV, d-slice wave*16

  const size_t bo = (size_t)bh * LL * DH;
  const float* qp = Q + bo;
  const float* kp = K + bo;
  const float* vp = V + bo;
  const int*   mrow = MSK + b * LL;

  unsigned char* ksh = kv + kh * 8192;           // this wave's K half-tile
  unsigned char* vth = kv + 16384 + kh * 8192;   // this wave's V^T half-tile

  // ---- Q^T B-frags, held in registers: qB[c] covers d = c*16 + hi*8 + j ----
  short8 qB[4];
#pragma unroll
  for (int c = 0; c < 4; ++c) {
    const float* src = qp + (size_t)irow * DH + c * 16 + hi * 8;
    qB[c] = pack8f(*(const float4*)src, *(const float4*)(src + 4));
  }

  // ---- mask pre-stage (whole 1024-k row of this b) ----
#pragma unroll
  for (int t2 = 0; t2 < 4; ++t2) {
    const int ix = tid + t2 * 256;
    mskf[ix] = mrow[ix] ? -INFINITY : 0.0f;
  }

  // ---- bias table: qR^T = pos . Q^T via MFMA; this wave: its qg rows,
  //      t-blocks tb = kh, kh+2, ... (5 of 10) ----
  for (int tb = kh; tb < 10; tb += 2) {
    int trow = tb * 32 + lo5; if (trow > 300) trow = 300;
    const float* pr = POS + (size_t)trow * DH;
    f32x16 z;
#pragma unroll
    for (int x = 0; x < 16; ++x) z[x] = 0.f;
#pragma unroll
    for (int c = 0; c < 4; ++c) {
      const float* s2 = pr + c * 16 + hi * 8;
      short8 af = pack8f(*(const float4*)s2, *(const float4*)(s2 + 4));
      z = __builtin_amdgcn_mfma_f32_32x32x16_bf16(af, qB[c], z, 0, 0, 0);
    }
#pragma unroll
    for (int rp = 0; rp < 8; ++rp) {
      const int r = rp * 2;
      int tp = KOFF(r) + 4 * hi + 32 * tb;
      if (tp < 306)  // keep junk cols inside the row (t<=300 ever read)
        *(unsigned*)(&qrs[qloc][tp]) = cvtpk(z[r], z[r + 1]);
    }
  }

  // ---- flash state (base-2 domain) ----
  const float SC = 0.18033688011112042f;  // 0.125 * log2(e)
  float m2 = -1e30f, lsum = 0.f;
  f32x16 acc0, acc1;
#pragma unroll
  for (int x = 0; x < 16; ++x) { acc0[x] = 0.f; acc1[x] = 0.f; }

  // ---- pipelined staging registers (T14) ----
  float4 kreg[2][4], vreg[2][4];
  auto LOADT = [&](int rdx) {
#pragma unroll
    for (int h = 0; h < 2; ++h) {
      const float* ksrc = kp + (size_t)(h * 512 + rdx * 64 + rK) * DH + q4 * 16;
#pragma unroll
      for (int i = 0; i < 4; ++i) kreg[h][i] = ((const float4*)ksrc)[i];
      const float* vsrc = vp + (size_t)(h * 512 + rdx * 64 + kkV) * DH + dwV * 16;
#pragma unroll
      for (int i = 0; i < 4; ++i) vreg[h][i] = ((const float4*)vsrc)[i];
    }
  };
  LOADT(0);

  for (int rd = 0; rd < 8; ++rd) {
    __syncthreads();  // prior round's ks/vt reads complete (covers table @rd=0)
    // ---- write staged regs -> LDS (bf16, swizzled) ----
#pragma unroll
    for (int h = 0; h < 2; ++h) {
      unsigned char* kb_ = kv + h * 8192;
      *(short8*)(kb_ + swz(rK, q4 * 32))      = pack8f(kreg[h][0], kreg[h][1]);
      *(short8*)(kb_ + swz(rK, q4 * 32 + 16)) = pack8f(kreg[h][2], kreg[h][3]);
      unsigned char* vb_ = kv + 16384 + h * 8192;
      const int db = dwV * 16, cb2 = kkV * 2;
      st_pair(vb_, db + 0,  cb2, vreg[h][0].x, vreg[h][0].y);
      st_pair(vb_, db + 2,  cb2, vreg[h][0].z, vreg[h][0].w);
      st_pair(vb_, db + 4,  cb2, vreg[h][1].x, vreg[h][1].y);
      st_pair(vb_, db + 6,  cb2, vreg[h][1].z, vreg[h][1].w);
      st_pair(vb_, db + 8,  cb2, vreg[h][2].x, vreg[h][2].y);
      st_pair(vb_, db + 10, cb2, vreg[h][2].z, vreg[h][2].w);
      st_pair(vb_, db + 12, cb2, vreg[h][3].x, vreg[h][3].y);
      st_pair(vb_, db + 14, cb2, vreg[h][3].z, vreg[h][3].w);
    }
    __syncthreads();
    if (rd < 7) LOADT(rd + 1);   // loads land during compute (T14)

    const int j0 = kh * 512 + rd * 64;

    // ---- S^T = K . Q^T (setprio hint around MFMA cluster, T5) ----
    f32x16 st[2];
    __builtin_amdgcn_s_setprio(1);
#pragma unroll
    for (int kb = 0; kb < 2; ++kb) {
      f32x16 z;
#pragma unroll
      for (int x = 0; x < 16; ++x) z[x] = 0.f;
#pragma unroll
      for (int c = 0; c < 4; ++c) {
        short8 kf = *(const short8*)(ksh + swz(kb * 32 + lo5, c * 32 + hi * 16));
        z = __builtin_amdgcn_mfma_f32_32x32x16_bf16(kf, qB[c], z, 0, 0, 0);
      }
      st[kb] = z;
    }
    __builtin_amdgcn_s_setprio(0);

    // ---- bias gather + scale + mask (lane owns q-row irow; k varies by reg) ----
#pragma unroll
    for (int kb = 0; kb < 2; ++kb) {
      const int jb = j0 + kb * 32;
      f32x4 mg[4];
#pragma unroll
      for (int g4 = 0; g4 < 4; ++g4)
        mg[g4] = *(const f32x4*)&mskf[jb + g4 * 8 + 4 * hi];
      const int relmin = jb - (i0 + qg * 32 + 31);
      const int relmax = jb + 31 - (i0 + qg * 32);
      if (relmin >= MAXL) {           // whole block saturates high -> idx 299
        const float bias = bf2f(qrs[qloc][299]);
#pragma unroll
        for (int r = 0; r < 16; ++r)
          st[kb][r] = (st[kb][r] + bias) * SC + mg[r >> 2][r & 3];
      } else if (relmax <= -MAXL) {   // saturates low -> wrap row 300
        const float bias = bf2f(qrs[qloc][300]);
#pragma unroll
        for (int r = 0; r < 16; ++r)
          st[kb][r] = (st[kb][r] + bias) * SC + mg[r >> 2][r & 3];
      } else {                        // near-diagonal: per-element gather
#pragma unroll
        for (int r = 0; r < 16; ++r) {
          const int rel = jb + KOFF(r) + 4 * hi - irow;
          const int idx = rel <= -MAXL ? 300 : (rel >= MAXL ? 299 : rel + MAXL - 1);
          st[kb][r] = (st[kb][r] + bf2f(qrs[qloc][idx])) * SC + mg[r >> 2][r & 3];
        }
      }
    }

    // ---- online softmax with defer-max (T13, base-2 THR=12) ----
    float mxa[16];
#pragma unroll
    for (int r = 0; r < 16; ++r) mxa[r] = fmaxf(st[0][r], st[1][r]);
    // max3-fused reduction over 16 (T17): 5+2 max3 + 1 fmax
    {
      const float t0 = max3f(mxa[0],  mxa[1],  mxa[2]);
      const float t1 = max3f(mxa[3],  mxa[4],  mxa[5]);
      const float t2 = max3f(mxa[6],  mxa[7],  mxa[8]);
      const float t3 = max3f(mxa[9],  mxa[10], mxa[11]);
      const float t4 = max3f(mxa[12], mxa[13], mxa[14]);
      const float u0 = max3f(t0, t1, t2);
      const float u1 = max3f(t3, t4, mxa[15]);
      mxa[0] = fmaxf(u0, u1);
    }
    const float tmax = fmaxf(mxa[0], __shfl_xor(mxa[0], 32));
    if (!__all(tmax - m2 <= 12.0f)) {
      const float mnew = fmaxf(m2, tmax);
      const float alpha = exp2f(m2 - mnew);
      lsum *= alpha;
      acc0 *= alpha; acc1 *= alpha;
      m2 = mnew;
    }
#pragma unroll
    for (int kb = 0; kb < 2; ++kb)
#pragma unroll
      for (int r = 0; r < 16; ++r) st[kb][r] = exp2f(st[kb][r] - m2);
    f32x16 sx;
#pragma unroll
    for (int r = 0; r < 16; ++r) sx[r] = st[0][r] + st[1][r];
#pragma unroll
    for (int w = 8; w > 0; w >>= 1)
#pragma unroll
      for (int r = 0; r < 8; ++r)
        if (r < w) sx[r] = sx[r] + sx[r + w];
    lsum += sx[0] + __shfl_xor(sx[0], 32);

    // ---- P^T frags in-register: cvt_pk pairs, exchange +-32 via shfl_xor ----
    short8 pf[4];
#pragma unroll
    for (int ch = 0; ch < 4; ++ch) {
      const int kb = ch >> 1, rb2 = (ch & 1) * 8;
      unsigned a  = cvtpk(st[kb][rb2 + 0], st[kb][rb2 + 1]);
      unsigned a2 = cvtpk(st[kb][rb2 + 2], st[kb][rb2 + 3]);
      unsigned bb = cvtpk(st[kb][rb2 + 4], st[kb][rb2 + 5]);
      unsigned b2 = cvtpk(st[kb][rb2 + 6], st[kb][rb2 + 7]);
      unsigned sa  = __shfl_xor(a, 32);
      unsigned sa2 = __shfl_xor(a2, 32);
      unsigned sbb = __shfl_xor(bb, 32);
      unsigned sb2 = __shfl_xor(b2, 32);
      U4S8 t;
      t.u[0] = hi ? sbb : a;    // k(0,1)  | k(8,9)
      t.u[1] = hi ? sb2 : a2;   // k(2,3)  | k(10,11)
      t.u[2] = hi ? bb  : sa;   // k(4,5)  | k(12,13)
      t.u[3] = hi ? b2  : sa2;  // k(6,7)  | k(14,15)
      pf[ch] = t.s;
    }

    // ---- PV: O^T += V^T . P^T (setprio hint around MFMA cluster, T5) ----
    __builtin_amdgcn_s_setprio(1);
#pragma unroll
    for (int ch = 0; ch < 4; ++ch) {
      short8 vf0 = *(const short8*)(vth + swz(lo5,      ch * 32 + hi * 16));
      short8 vf1 = *(const short8*)(vth + swz(32 + lo5, ch * 32 + hi * 16));
      acc0 = __builtin_amdgcn_mfma_f32_32x32x16_bf16(vf0, pf[ch], acc0, 0, 0, 0);
      acc1 = __builtin_amdgcn_mfma_f32_32x32x16_bf16(vf1, pf[ch], acc1, 0, 0, 0);
    }
    __builtin_amdgcn_s_setprio(0);
  }

  // ---- k-half merge (flash combine) + epilogue ----
  __syncthreads();
  float* mb = (float*)kv;  // reuse K/V LDS: 128 lanes * 37 f32 = 18944 B
  if (wave >= 2) {
    float* d = mb + ((wave - 2) * 64 + lane) * 37;
    d[0] = m2; d[1] = lsum;
#pragma unroll
    for (int r = 0; r < 16; ++r) { d[2 + r] = acc0[r]; d[18 + r] = acc1[r]; }
  }
  __syncthreads();
  if (wave < 2) {
    const float* d = mb + (wave * 64 + lane) * 37;
    const float m1 = d[0], l1 = d[1];
    const float mf = fmaxf(m2, m1);
    const float a0 = exp2f(m2 - mf), a1 = exp2f(m1 - mf);
    const float lf = lsum * a0 + l1 * a1;
    const float inv = 1.f / lf;
    float* op = OUT + bo + (size_t)irow * DH;
#pragma unroll
    for (int r = 0; r < 16; ++r) {
      const int d0 = KOFF(r) + 4 * hi;
      op[d0]      = (acc0[r] * a0 + d[2 + r]  * a1) * inv;
      op[d0 + 32] = (acc1[r] * a0 + d[18 + r] * a1) * inv;
    }
  }
}

extern "C" void kernel_launch(void* const* d_in, const int* in_sizes, int n_in,
                              void* d_out, int out_size, void* d_ws, size_t ws_size,
                              hipStream_t stream) {
  const float* q   = (const float*)d_in[0];
  const float* k   = (const float*)d_in[1];
  const float* v   = (const float*)d_in[2];
  const float* pos = (const float*)d_in[3];
  const int*   msk = (const int*)d_in[4];
  float* out = (float*)d_out;

  rp_attn32<<<dim3(1024), dim3(256), 0, stream>>>(q, k, v, pos, msk, out);
}

// Round 14
// 89.769 us; speedup vs baseline: 2.2744x; 1.0800x over previous
//
#include <hip/hip_runtime.h>
#include <math.h>

// RP scaled-dot-product attention, swapped-QK^T 32x32x16 MFMA flash kernel.
// B=4 H=16 L=1024 Dh=64.  One WG (256 thr, 4 waves) per (bh, 64-query tile).
// Round 14 = VERIFIED round-6 kernel (95.1 us, session best) restored exactly,
// with ONE compute-side-only delta: exp2 via __builtin_amdgcn_exp2f (bare
// v_exp_f32, ~1 ulp) instead of libm exp2f, eliminating any guard-sequence
// expansion on the 32 exp calls per lane per iteration.
//
// 32x32x16 bf16 layouts (C verified m74/m101):
//   A: lane l holds A[l&31][(l>>5)*8+j]   B: lane l holds B[(l>>5)*8+j][l&31]
//   C: lane l reg r holds C[(r&3)+8*(r>>2)+4*(l>>5)][l&31]

#define LL 1024
#define DH 64
#define MAXL 150

typedef __attribute__((ext_vector_type(8)))  short    short8;
typedef __attribute__((ext_vector_type(4)))  float    f32x4;
typedef __attribute__((ext_vector_type(16))) float    f32x16;
typedef __attribute__((ext_vector_type(4)))  unsigned u32x4;

union U4S8 { u32x4 u; short8 s; };

__device__ __forceinline__ unsigned cvtpk(float lo, float hi) {
  unsigned r;
  asm("v_cvt_pk_bf16_f32 %0, %1, %2" : "=v"(r) : "v"(lo), "v"(hi));
  return r;
}
__device__ __forceinline__ float bf2f(unsigned short s) {
  return __uint_as_float((unsigned)s << 16);
}
__device__ __forceinline__ float exp2h(float x) {
#if __has_builtin(__builtin_amdgcn_exp2f)
  return __builtin_amdgcn_exp2f(x);   // bare v_exp_f32
#else
  return exp2f(x);
#endif
}
__device__ __forceinline__ short8 pack8f(float4 a, float4 b) {
  U4S8 t;
  t.u[0] = cvtpk(a.x, a.y); t.u[1] = cvtpk(a.z, a.w);
  t.u[2] = cvtpk(b.x, b.y); t.u[3] = cvtpk(b.z, b.w);
  return t.s;
}
// byte offset in a 128B-row LDS tile, XOR-swizzled (G4)
__device__ __forceinline__ int swz(int row, int cb) {
  return row * 128 + (cb ^ ((row & 7) << 4));
}
__device__ __forceinline__ void st_pair(unsigned char* base, int row, int colb,
                                        float a, float b) {
  unsigned u = cvtpk(a, b);
  *(unsigned short*)(base + swz(row, colb))     = (unsigned short)u;
  *(unsigned short*)(base + swz(row + 1, colb)) = (unsigned short)(u >> 16);
}
#define KOFF(r) ((((r) & 3)) + 8 * ((r) >> 2))

__global__ __launch_bounds__(256, 2)
void rp_attn32(const float* __restrict__ Q, const float* __restrict__ K,
               const float* __restrict__ V, const float* __restrict__ POS,
               const int* __restrict__ MSK, float* __restrict__ OUT) {
  // qrs: bias table, row stride 306 u16 = 612 B (odd dword stride)
  __shared__ __attribute__((aligned(16))) unsigned short qrs[64][306]; // 39168 B
  __shared__ __attribute__((aligned(16))) unsigned char  kv[32768];    // K h0,h1 | V^T h0,h1
  __shared__ __attribute__((aligned(16))) float          mskf[1024];   // 4096 B

  const int tid = threadIdx.x;
  // XCD-chunked swizzle: XCD d serves bh in [8d,8d+8) -> K/V fits its 4MB L2
  const int F  = blockIdx.x;
  const int gi = F >> 3;
  const int bh = (F & 7) * 8 + (gi >> 4);
  const int i0 = (gi & 15) * 64;
  const int b  = bh >> 4;

  const int wave = tid >> 6, lane = tid & 63;
  const int lo5 = lane & 31, hi = lane >> 5;
  const int qg = wave & 1, kh = wave >> 1;   // q-group, k-half
  const int qloc = qg * 32 + lo5;
  const int irow = i0 + qloc;

  // staging thread mappings
  const int rK = tid >> 2, q4 = tid & 3;     // K: row rK, d-slice q4*16
  const int kkV = tid & 63, dwV = wave;      // V: row kkV, d-slice wave*16

  const size_t bo = (size_t)bh * LL * DH;
  const float* qp = Q + bo;
  const float* kp = K + bo;
  const float* vp = V + bo;
  const int*   mrow = MSK + b * LL;

  unsigned char* ksh = kv + kh * 8192;           // this wave's K half-tile
  unsigned char* vth = kv + 16384 + kh * 8192;   // this wave's V^T half-tile

  // ---- Q^T B-frags, held in registers: qB[c] covers d = c*16 + hi*8 + j ----
  short8 qB[4];
#pragma unroll
  for (int c = 0; c < 4; ++c) {
    const float* src = qp + (size_t)irow * DH + c * 16 + hi * 8;
    qB[c] = pack8f(*(const float4*)src, *(const float4*)(src + 4));
  }

  // ---- mask pre-stage (whole 1024-k row of this b) ----
#pragma unroll
  for (int t2 = 0; t2 < 4; ++t2) {
    const int ix = tid + t2 * 256;
    mskf[ix] = mrow[ix] ? -INFINITY : 0.0f;
  }

  // ---- bias table: qR^T = pos . Q^T via MFMA; this wave: its qg rows,
  //      t-blocks tb = kh, kh+2, ... (5 of 10) ----
  for (int tb = kh; tb < 10; tb += 2) {
    int trow = tb * 32 + lo5; if (trow > 300) trow = 300;
    const float* pr = POS + (size_t)trow * DH;
    f32x16 z;
#pragma unroll
    for (int x = 0; x < 16; ++x) z[x] = 0.f;
#pragma unroll
    for (int c = 0; c < 4; ++c) {
      const float* s2 = pr + c * 16 + hi * 8;
      short8 af = pack8f(*(const float4*)s2, *(const float4*)(s2 + 4));
      z = __builtin_amdgcn_mfma_f32_32x32x16_bf16(af, qB[c], z, 0, 0, 0);
    }
#pragma unroll
    for (int rp = 0; rp < 8; ++rp) {
      const int r = rp * 2;
      int tp = KOFF(r) + 4 * hi + 32 * tb;
      if (tp < 306)  // keep junk cols inside the row (t<=300 ever read)
        *(unsigned*)(&qrs[qloc][tp]) = cvtpk(z[r], z[r + 1]);
    }
  }

  // ---- flash state (base-2 domain) ----
  const float SC = 0.18033688011112042f;  // 0.125 * log2(e)
  float m2 = -1e30f, lsum = 0.f;
  f32x16 acc0, acc1;
#pragma unroll
  for (int x = 0; x < 16; ++x) { acc0[x] = 0.f; acc1[x] = 0.f; }

  // ---- pipelined staging registers (T14) ----
  float4 kreg[2][4], vreg[2][4];
  auto LOADT = [&](int rdx) {
#pragma unroll
    for (int h = 0; h < 2; ++h) {
      const float* ksrc = kp + (size_t)(h * 512 + rdx * 64 + rK) * DH + q4 * 16;
#pragma unroll
      for (int i = 0; i < 4; ++i) kreg[h][i] = ((const float4*)ksrc)[i];
      const float* vsrc = vp + (size_t)(h * 512 + rdx * 64 + kkV) * DH + dwV * 16;
#pragma unroll
      for (int i = 0; i < 4; ++i) vreg[h][i] = ((const float4*)vsrc)[i];
    }
  };
  LOADT(0);

  for (int rd = 0; rd < 8; ++rd) {
    __syncthreads();  // prior round's ks/vt reads complete (covers table @rd=0)
    // ---- write staged regs -> LDS (bf16, swizzled) ----
#pragma unroll
    for (int h = 0; h < 2; ++h) {
      unsigned char* kb_ = kv + h * 8192;
      *(short8*)(kb_ + swz(rK, q4 * 32))      = pack8f(kreg[h][0], kreg[h][1]);
      *(short8*)(kb_ + swz(rK, q4 * 32 + 16)) = pack8f(kreg[h][2], kreg[h][3]);
      unsigned char* vb_ = kv + 16384 + h * 8192;
      const int db = dwV * 16, cb2 = kkV * 2;
      st_pair(vb_, db + 0,  cb2, vreg[h][0].x, vreg[h][0].y);
      st_pair(vb_, db + 2,  cb2, vreg[h][0].z, vreg[h][0].w);
      st_pair(vb_, db + 4,  cb2, vreg[h][1].x, vreg[h][1].y);
      st_pair(vb_, db + 6,  cb2, vreg[h][1].z, vreg[h][1].w);
      st_pair(vb_, db + 8,  cb2, vreg[h][2].x, vreg[h][2].y);
      st_pair(vb_, db + 10, cb2, vreg[h][2].z, vreg[h][2].w);
      st_pair(vb_, db + 12, cb2, vreg[h][3].x, vreg[h][3].y);
      st_pair(vb_, db + 14, cb2, vreg[h][3].z, vreg[h][3].w);
    }
    __syncthreads();
    if (rd < 7) LOADT(rd + 1);   // loads land during compute (T14)

    const int j0 = kh * 512 + rd * 64;

    // ---- S^T = K . Q^T ----
    f32x16 st[2];
#pragma unroll
    for (int kb = 0; kb < 2; ++kb) {
      f32x16 z;
#pragma unroll
      for (int x = 0; x < 16; ++x) z[x] = 0.f;
#pragma unroll
      for (int c = 0; c < 4; ++c) {
        short8 kf = *(const short8*)(ksh + swz(kb * 32 + lo5, c * 32 + hi * 16));
        z = __builtin_amdgcn_mfma_f32_32x32x16_bf16(kf, qB[c], z, 0, 0, 0);
      }
      st[kb] = z;
    }

    // ---- bias gather + scale + mask (lane owns q-row irow; k varies by reg) ----
#pragma unroll
    for (int kb = 0; kb < 2; ++kb) {
      const int jb = j0 + kb * 32;
      f32x4 mg[4];
#pragma unroll
      for (int g4 = 0; g4 < 4; ++g4)
        mg[g4] = *(const f32x4*)&mskf[jb + g4 * 8 + 4 * hi];
      const int relmin = jb - (i0 + qg * 32 + 31);
      const int relmax = jb + 31 - (i0 + qg * 32);
      if (relmin >= MAXL) {           // whole block saturates high -> idx 299
        const float bias = bf2f(qrs[qloc][299]);
#pragma unroll
        for (int r = 0; r < 16; ++r)
          st[kb][r] = (st[kb][r] + bias) * SC + mg[r >> 2][r & 3];
      } else if (relmax <= -MAXL) {   // saturates low -> wrap row 300
        const float bias = bf2f(qrs[qloc][300]);
#pragma unroll
        for (int r = 0; r < 16; ++r)
          st[kb][r] = (st[kb][r] + bias) * SC + mg[r >> 2][r & 3];
      } else {                        // near-diagonal: per-element gather
#pragma unroll
        for (int r = 0; r < 16; ++r) {
          const int rel = jb + KOFF(r) + 4 * hi - irow;
          const int idx = rel <= -MAXL ? 300 : (rel >= MAXL ? 299 : rel + MAXL - 1);
          st[kb][r] = (st[kb][r] + bf2f(qrs[qloc][idx])) * SC + mg[r >> 2][r & 3];
        }
      }
    }

    // ---- online softmax with defer-max (T13, base-2 THR=12) ----
    f32x16 mx;
#pragma unroll
    for (int r = 0; r < 16; ++r) mx[r] = fmaxf(st[0][r], st[1][r]);
#pragma unroll
    for (int w = 8; w > 0; w >>= 1)
#pragma unroll
      for (int r = 0; r < 8; ++r)
        if (r < w) mx[r] = fmaxf(mx[r], mx[r + w]);
    const float tmax = fmaxf(mx[0], __shfl_xor(mx[0], 32));
    if (!__all(tmax - m2 <= 12.0f)) {
      const float mnew = fmaxf(m2, tmax);
      const float alpha = exp2h(m2 - mnew);
      lsum *= alpha;
      acc0 *= alpha; acc1 *= alpha;
      m2 = mnew;
    }
#pragma unroll
    for (int kb = 0; kb < 2; ++kb)
#pragma unroll
      for (int r = 0; r < 16; ++r) st[kb][r] = exp2h(st[kb][r] - m2);
    f32x16 sx;
#pragma unroll
    for (int r = 0; r < 16; ++r) sx[r] = st[0][r] + st[1][r];
#pragma unroll
    for (int w = 8; w > 0; w >>= 1)
#pragma unroll
      for (int r = 0; r < 8; ++r)
        if (r < w) sx[r] = sx[r] + sx[r + w];
    lsum += sx[0] + __shfl_xor(sx[0], 32);

    // ---- P^T frags in-register: cvt_pk pairs, exchange +-32 via shfl_xor ----
    short8 pf[4];
#pragma unroll
    for (int ch = 0; ch < 4; ++ch) {
      const int kb = ch >> 1, rb2 = (ch & 1) * 8;
      unsigned a  = cvtpk(st[kb][rb2 + 0], st[kb][rb2 + 1]);
      unsigned a2 = cvtpk(st[kb][rb2 + 2], st[kb][rb2 + 3]);
      unsigned bb = cvtpk(st[kb][rb2 + 4], st[kb][rb2 + 5]);
      unsigned b2 = cvtpk(st[kb][rb2 + 6], st[kb][rb2 + 7]);
      unsigned sa  = __shfl_xor(a, 32);
      unsigned sa2 = __shfl_xor(a2, 32);
      unsigned sbb = __shfl_xor(bb, 32);
      unsigned sb2 = __shfl_xor(b2, 32);
      U4S8 t;
      t.u[0] = hi ? sbb : a;    // k(0,1)  | k(8,9)
      t.u[1] = hi ? sb2 : a2;   // k(2,3)  | k(10,11)
      t.u[2] = hi ? bb  : sa;   // k(4,5)  | k(12,13)
      t.u[3] = hi ? b2  : sa2;  // k(6,7)  | k(14,15)
      pf[ch] = t.s;
    }

    // ---- PV: O^T += V^T . P^T ----
#pragma unroll
    for (int ch = 0; ch < 4; ++ch) {
      short8 vf0 = *(const short8*)(vth + swz(lo5,      ch * 32 + hi * 16));
      short8 vf1 = *(const short8*)(vth + swz(32 + lo5, ch * 32 + hi * 16));
      acc0 = __builtin_amdgcn_mfma_f32_32x32x16_bf16(vf0, pf[ch], acc0, 0, 0, 0);
      acc1 = __builtin_amdgcn_mfma_f32_32x32x16_bf16(vf1, pf[ch], acc1, 0, 0, 0);
    }
  }

  // ---- k-half merge (flash combine) + epilogue ----
  __syncthreads();
  float* mb = (float*)kv;  // reuse K/V LDS: 128 lanes * 37 f32 = 18944 B
  if (wave >= 2) {
    float* d = mb + ((wave - 2) * 64 + lane) * 37;
    d[0] = m2; d[1] = lsum;
#pragma unroll
    for (int r = 0; r < 16; ++r) { d[2 + r] = acc0[r]; d[18 + r] = acc1[r]; }
  }
  __syncthreads();
  if (wave < 2) {
    const float* d = mb + (wave * 64 + lane) * 37;
    const float m1 = d[0], l1 = d[1];
    const float mf = fmaxf(m2, m1);
    const float a0 = exp2h(m2 - mf), a1 = exp2h(m1 - mf);
    const float lf = lsum * a0 + l1 * a1;
    const float inv = 1.f / lf;
    float* op = OUT + bo + (size_t)irow * DH;
#pragma unroll
    for (int r = 0; r < 16; ++r) {
      const int d0 = KOFF(r) + 4 * hi;
      op[d0]      = (acc0[r] * a0 + d[2 + r]  * a1) * inv;
      op[d0 + 32] = (acc1[r] * a0 + d[18 + r] * a1) * inv;
    }
  }
}

extern "C" void kernel_launch(void* const* d_in, const int* in_sizes, int n_in,
                              void* d_out, int out_size, void* d_ws, size_t ws_size,
                              hipStream_t stream) {
  const float* q   = (const float*)d_in[0];
  const float* k   = (const float*)d_in[1];
  const float* v   = (const float*)d_in[2];
  const float* pos = (const float*)d_in[3];
  const int*   msk = (const int*)d_in[4];
  float* out = (float*)d_out;

  rp_attn32<<<dim3(1024), dim3(256), 0, stream>>>(q, k, v, pos, msk, out);
}

// Round 16
// 89.689 us; speedup vs baseline: 2.2764x; 1.0009x over previous
//
#include <hip/hip_runtime.h>
#include <math.h>

// RP scaled-dot-product attention, swapped-QK^T 32x32x16 MFMA flash kernel.
// B=4 H=16 L=1024 Dh=64.  One WG (256 thr, 4 waves) per (bh, 64-query tile).
// Round 16 = RESTORE of the verified round-14 kernel (89.8 us session best),
// byte-identical. R15's ILP hoists reproduced the toolchain corruption
// (absmax 1.056641, identical to R3/R11/R13): the failure class is "new
// values held live across the softmax region" (register-lifetime extension
// past ~128 live VGPRs with the cvtpk inline-asm present). This kernel keeps
// the verified register schedule.
//
// 32x32x16 bf16 layouts (C verified m74/m101):
//   A: lane l holds A[l&31][(l>>5)*8+j]   B: lane l holds B[(l>>5)*8+j][l&31]
//   C: lane l reg r holds C[(r&3)+8*(r>>2)+4*(l>>5)][l&31]

#define LL 1024
#define DH 64
#define MAXL 150

typedef __attribute__((ext_vector_type(8)))  short    short8;
typedef __attribute__((ext_vector_type(4)))  float    f32x4;
typedef __attribute__((ext_vector_type(16))) float    f32x16;
typedef __attribute__((ext_vector_type(4)))  unsigned u32x4;

union U4S8 { u32x4 u; short8 s; };

__device__ __forceinline__ unsigned cvtpk(float lo, float hi) {
  unsigned r;
  asm("v_cvt_pk_bf16_f32 %0, %1, %2" : "=v"(r) : "v"(lo), "v"(hi));
  return r;
}
__device__ __forceinline__ float bf2f(unsigned short s) {
  return __uint_as_float((unsigned)s << 16);
}
__device__ __forceinline__ float exp2h(float x) {
#if __has_builtin(__builtin_amdgcn_exp2f)
  return __builtin_amdgcn_exp2f(x);   // bare v_exp_f32
#else
  return exp2f(x);
#endif
}
__device__ __forceinline__ short8 pack8f(float4 a, float4 b) {
  U4S8 t;
  t.u[0] = cvtpk(a.x, a.y); t.u[1] = cvtpk(a.z, a.w);
  t.u[2] = cvtpk(b.x, b.y); t.u[3] = cvtpk(b.z, b.w);
  return t.s;
}
// byte offset in a 128B-row LDS tile, XOR-swizzled (G4)
__device__ __forceinline__ int swz(int row, int cb) {
  return row * 128 + (cb ^ ((row & 7) << 4));
}
__device__ __forceinline__ void st_pair(unsigned char* base, int row, int colb,
                                        float a, float b) {
  unsigned u = cvtpk(a, b);
  *(unsigned short*)(base + swz(row, colb))     = (unsigned short)u;
  *(unsigned short*)(base + swz(row + 1, colb)) = (unsigned short)(u >> 16);
}
#define KOFF(r) ((((r) & 3)) + 8 * ((r) >> 2))

__global__ __launch_bounds__(256, 2)
void rp_attn32(const float* __restrict__ Q, const float* __restrict__ K,
               const float* __restrict__ V, const float* __restrict__ POS,
               const int* __restrict__ MSK, float* __restrict__ OUT) {
  // qrs: bias table, row stride 306 u16 = 612 B (odd dword stride)
  __shared__ __attribute__((aligned(16))) unsigned short qrs[64][306]; // 39168 B
  __shared__ __attribute__((aligned(16))) unsigned char  kv[32768];    // K h0,h1 | V^T h0,h1
  __shared__ __attribute__((aligned(16))) float          mskf[1024];   // 4096 B

  const int tid = threadIdx.x;
  // XCD-chunked swizzle: XCD d serves bh in [8d,8d+8) -> K/V fits its 4MB L2
  const int F  = blockIdx.x;
  const int gi = F >> 3;
  const int bh = (F & 7) * 8 + (gi >> 4);
  const int i0 = (gi & 15) * 64;
  const int b  = bh >> 4;

  const int wave = tid >> 6, lane = tid & 63;
  const int lo5 = lane & 31, hi = lane >> 5;
  const int qg = wave & 1, kh = wave >> 1;   // q-group, k-half
  const int qloc = qg * 32 + lo5;
  const int irow = i0 + qloc;

  // staging thread mappings
  const int rK = tid >> 2, q4 = tid & 3;     // K: row rK, d-slice q4*16
  const int kkV = tid & 63, dwV = wave;      // V: row kkV, d-slice wave*16

  const size_t bo = (size_t)bh * LL * DH;
  const float* qp = Q + bo;
  const float* kp = K + bo;
  const float* vp = V + bo;
  const int*   mrow = MSK + b * LL;

  unsigned char* ksh = kv + kh * 8192;           // this wave's K half-tile
  unsigned char* vth = kv + 16384 + kh * 8192;   // this wave's V^T half-tile

  // ---- Q^T B-frags, held in registers: qB[c] covers d = c*16 + hi*8 + j ----
  short8 qB[4];
#pragma unroll
  for (int c = 0; c < 4; ++c) {
    const float* src = qp + (size_t)irow * DH + c * 16 + hi * 8;
    qB[c] = pack8f(*(const float4*)src, *(const float4*)(src + 4));
  }

  // ---- mask pre-stage (whole 1024-k row of this b) ----
#pragma unroll
  for (int t2 = 0; t2 < 4; ++t2) {
    const int ix = tid + t2 * 256;
    mskf[ix] = mrow[ix] ? -INFINITY : 0.0f;
  }

  // ---- bias table: qR^T = pos . Q^T via MFMA; this wave: its qg rows,
  //      t-blocks tb = kh, kh+2, ... (5 of 10) ----
  for (int tb = kh; tb < 10; tb += 2) {
    int trow = tb * 32 + lo5; if (trow > 300) trow = 300;
    const float* pr = POS + (size_t)trow * DH;
    f32x16 z;
#pragma unroll
    for (int x = 0; x < 16; ++x) z[x] = 0.f;
#pragma unroll
    for (int c = 0; c < 4; ++c) {
      const float* s2 = pr + c * 16 + hi * 8;
      short8 af = pack8f(*(const float4*)s2, *(const float4*)(s2 + 4));
      z = __builtin_amdgcn_mfma_f32_32x32x16_bf16(af, qB[c], z, 0, 0, 0);
    }
#pragma unroll
    for (int rp = 0; rp < 8; ++rp) {
      const int r = rp * 2;
      int tp = KOFF(r) + 4 * hi + 32 * tb;
      if (tp < 306)  // keep junk cols inside the row (t<=300 ever read)
        *(unsigned*)(&qrs[qloc][tp]) = cvtpk(z[r], z[r + 1]);
    }
  }

  // ---- flash state (base-2 domain) ----
  const float SC = 0.18033688011112042f;  // 0.125 * log2(e)
  float m2 = -1e30f, lsum = 0.f;
  f32x16 acc0, acc1;
#pragma unroll
  for (int x = 0; x < 16; ++x) { acc0[x] = 0.f; acc1[x] = 0.f; }

  // ---- pipelined staging registers (T14) ----
  float4 kreg[2][4], vreg[2][4];
  auto LOADT = [&](int rdx) {
#pragma unroll
    for (int h = 0; h < 2; ++h) {
      const float* ksrc = kp + (size_t)(h * 512 + rdx * 64 + rK) * DH + q4 * 16;
#pragma unroll
      for (int i = 0; i < 4; ++i) kreg[h][i] = ((const float4*)ksrc)[i];
      const float* vsrc = vp + (size_t)(h * 512 + rdx * 64 + kkV) * DH + dwV * 16;
#pragma unroll
      for (int i = 0; i < 4; ++i) vreg[h][i] = ((const float4*)vsrc)[i];
    }
  };
  LOADT(0);

  for (int rd = 0; rd < 8; ++rd) {
    __syncthreads();  // prior round's ks/vt reads complete (covers table @rd=0)
    // ---- write staged regs -> LDS (bf16, swizzled) ----
#pragma unroll
    for (int h = 0; h < 2; ++h) {
      unsigned char* kb_ = kv + h * 8192;
      *(short8*)(kb_ + swz(rK, q4 * 32))      = pack8f(kreg[h][0], kreg[h][1]);
      *(short8*)(kb_ + swz(rK, q4 * 32 + 16)) = pack8f(kreg[h][2], kreg[h][3]);
      unsigned char* vb_ = kv + 16384 + h * 8192;
      const int db = dwV * 16, cb2 = kkV * 2;
      st_pair(vb_, db + 0,  cb2, vreg[h][0].x, vreg[h][0].y);
      st_pair(vb_, db + 2,  cb2, vreg[h][0].z, vreg[h][0].w);
      st_pair(vb_, db + 4,  cb2, vreg[h][1].x, vreg[h][1].y);
      st_pair(vb_, db + 6,  cb2, vreg[h][1].z, vreg[h][1].w);
      st_pair(vb_, db + 8,  cb2, vreg[h][2].x, vreg[h][2].y);
      st_pair(vb_, db + 10, cb2, vreg[h][2].z, vreg[h][2].w);
      st_pair(vb_, db + 12, cb2, vreg[h][3].x, vreg[h][3].y);
      st_pair(vb_, db + 14, cb2, vreg[h][3].z, vreg[h][3].w);
    }
    __syncthreads();
    if (rd < 7) LOADT(rd + 1);   // loads land during compute (T14)

    const int j0 = kh * 512 + rd * 64;

    // ---- S^T = K . Q^T ----
    f32x16 st[2];
#pragma unroll
    for (int kb = 0; kb < 2; ++kb) {
      f32x16 z;
#pragma unroll
      for (int x = 0; x < 16; ++x) z[x] = 0.f;
#pragma unroll
      for (int c = 0; c < 4; ++c) {
        short8 kf = *(const short8*)(ksh + swz(kb * 32 + lo5, c * 32 + hi * 16));
        z = __builtin_amdgcn_mfma_f32_32x32x16_bf16(kf, qB[c], z, 0, 0, 0);
      }
      st[kb] = z;
    }

    // ---- bias gather + scale + mask (lane owns q-row irow; k varies by reg) ----
#pragma unroll
    for (int kb = 0; kb < 2; ++kb) {
      const int jb = j0 + kb * 32;
      f32x4 mg[4];
#pragma unroll
      for (int g4 = 0; g4 < 4; ++g4)
        mg[g4] = *(const f32x4*)&mskf[jb + g4 * 8 + 4 * hi];
      const int relmin = jb - (i0 + qg * 32 + 31);
      const int relmax = jb + 31 - (i0 + qg * 32);
      if (relmin >= MAXL) {           // whole block saturates high -> idx 299
        const float bias = bf2f(qrs[qloc][299]);
#pragma unroll
        for (int r = 0; r < 16; ++r)
          st[kb][r] = (st[kb][r] + bias) * SC + mg[r >> 2][r & 3];
      } else if (relmax <= -MAXL) {   // saturates low -> wrap row 300
        const float bias = bf2f(qrs[qloc][300]);
#pragma unroll
        for (int r = 0; r < 16; ++r)
          st[kb][r] = (st[kb][r] + bias) * SC + mg[r >> 2][r & 3];
      } else {                        // near-diagonal: per-element gather
#pragma unroll
        for (int r = 0; r < 16; ++r) {
          const int rel = jb + KOFF(r) + 4 * hi - irow;
          const int idx = rel <= -MAXL ? 300 : (rel >= MAXL ? 299 : rel + MAXL - 1);
          st[kb][r] = (st[kb][r] + bf2f(qrs[qloc][idx])) * SC + mg[r >> 2][r & 3];
        }
      }
    }

    // ---- online softmax with defer-max (T13, base-2 THR=12) ----
    f32x16 mx;
#pragma unroll
    for (int r = 0; r < 16; ++r) mx[r] = fmaxf(st[0][r], st[1][r]);
#pragma unroll
    for (int w = 8; w > 0; w >>= 1)
#pragma unroll
      for (int r = 0; r < 8; ++r)
        if (r < w) mx[r] = fmaxf(mx[r], mx[r + w]);
    const float tmax = fmaxf(mx[0], __shfl_xor(mx[0], 32));
    if (!__all(tmax - m2 <= 12.0f)) {
      const float mnew = fmaxf(m2, tmax);
      const float alpha = exp2h(m2 - mnew);
      lsum *= alpha;
      acc0 *= alpha; acc1 *= alpha;
      m2 = mnew;
    }
#pragma unroll
    for (int kb = 0; kb < 2; ++kb)
#pragma unroll
      for (int r = 0; r < 16; ++r) st[kb][r] = exp2h(st[kb][r] - m2);
    f32x16 sx;
#pragma unroll
    for (int r = 0; r < 16; ++r) sx[r] = st[0][r] + st[1][r];
#pragma unroll
    for (int w = 8; w > 0; w >>= 1)
#pragma unroll
      for (int r = 0; r < 8; ++r)
        if (r < w) sx[r] = sx[r] + sx[r + w];
    lsum += sx[0] + __shfl_xor(sx[0], 32);

    // ---- P^T frags in-register: cvt_pk pairs, exchange +-32 via shfl_xor ----
    short8 pf[4];
#pragma unroll
    for (int ch = 0; ch < 4; ++ch) {
      const int kb = ch >> 1, rb2 = (ch & 1) * 8;
      unsigned a  = cvtpk(st[kb][rb2 + 0], st[kb][rb2 + 1]);
      unsigned a2 = cvtpk(st[kb][rb2 + 2], st[kb][rb2 + 3]);
      unsigned bb = cvtpk(st[kb][rb2 + 4], st[kb][rb2 + 5]);
      unsigned b2 = cvtpk(st[kb][rb2 + 6], st[kb][rb2 + 7]);
      unsigned sa  = __shfl_xor(a, 32);
      unsigned sa2 = __shfl_xor(a2, 32);
      unsigned sbb = __shfl_xor(bb, 32);
      unsigned sb2 = __shfl_xor(b2, 32);
      U4S8 t;
      t.u[0] = hi ? sbb : a;    // k(0,1)  | k(8,9)
      t.u[1] = hi ? sb2 : a2;   // k(2,3)  | k(10,11)
      t.u[2] = hi ? bb  : sa;   // k(4,5)  | k(12,13)
      t.u[3] = hi ? b2  : sa2;  // k(6,7)  | k(14,15)
      pf[ch] = t.s;
    }

    // ---- PV: O^T += V^T . P^T ----
#pragma unroll
    for (int ch = 0; ch < 4; ++ch) {
      short8 vf0 = *(const short8*)(vth + swz(lo5,      ch * 32 + hi * 16));
      short8 vf1 = *(const short8*)(vth + swz(32 + lo5, ch * 32 + hi * 16));
      acc0 = __builtin_amdgcn_mfma_f32_32x32x16_bf16(vf0, pf[ch], acc0, 0, 0, 0);
      acc1 = __builtin_amdgcn_mfma_f32_32x32x16_bf16(vf1, pf[ch], acc1, 0, 0, 0);
    }
  }

  // ---- k-half merge (flash combine) + epilogue ----
  __syncthreads();
  float* mb = (float*)kv;  // reuse K/V LDS: 128 lanes * 37 f32 = 18944 B
  if (wave >= 2) {
    float* d = mb + ((wave - 2) * 64 + lane) * 37;
    d[0] = m2; d[1] = lsum;
#pragma unroll
    for (int r = 0; r < 16; ++r) { d[2 + r] = acc0[r]; d[18 + r] = acc1[r]; }
  }
  __syncthreads();
  if (wave < 2) {
    const float* d = mb + (wave * 64 + lane) * 37;
    const float m1 = d[0], l1 = d[1];
    const float mf = fmaxf(m2, m1);
    const float a0 = exp2h(m2 - mf), a1 = exp2h(m1 - mf);
    const float lf = lsum * a0 + l1 * a1;
    const float inv = 1.f / lf;
    float* op = OUT + bo + (size_t)irow * DH;
#pragma unroll
    for (int r = 0; r < 16; ++r) {
      const int d0 = KOFF(r) + 4 * hi;
      op[d0]      = (acc0[r] * a0 + d[2 + r]  * a1) * inv;
      op[d0 + 32] = (acc1[r] * a0 + d[18 + r] * a1) * inv;
    }
  }
}

extern "C" void kernel_launch(void* const* d_in, const int* in_sizes, int n_in,
                              void* d_out, int out_size, void* d_ws, size_t ws_size,
                              hipStream_t stream) {
  const float* q   = (const float*)d_in[0];
  const float* k   = (const float*)d_in[1];
  const float* v   = (const float*)d_in[2];
  const float* pos = (const float*)d_in[3];
  const int*   msk = (const int*)d_in[4];
  float* out = (float*)d_out;

  rp_attn32<<<dim3(1024), dim3(256), 0, stream>>>(q, k, v, pos, msk, out);
}